// Round 4
// baseline (66.476 us; speedup 1.0000x reference)
//
#include <hip/hip_runtime.h>

#define LEAKY_S 0.01f
#define BN_EPS 1e-5f
#define LOG2E 1.44269504088896340736f

typedef float f32x2 __attribute__((ext_vector_type(2)));
typedef float f32x4 __attribute__((ext_vector_type(4)));

__device__ __forceinline__ float leaky(float v) { return v >= 0.0f ? v : LEAKY_S * v; }
__device__ __forceinline__ float fast_exp2(float v) { return __builtin_amdgcn_exp2f(v); }
// sigmoid(z) with weights pre-scaled by log2e
__device__ __forceinline__ float sig2(float z2) {
    return __builtin_amdgcn_rcpf(1.0f + fast_exp2(-z2));
}
__device__ __forceinline__ void st2(float* p, float a, float b) {
    f32x2 v = {a, b}; *(f32x2*)p = v;
}
__device__ __forceinline__ void st_nt2(float* p, float a, float b) {
    f32x2 v = {a, b}; __builtin_nontemporal_store(v, (f32x2*)p);
}
__device__ __forceinline__ void st_nt4(float* p, float a, float b, float c, float d) {
    f32x4 v = {a, b, c, d}; __builtin_nontemporal_store(v, (f32x4*)p);
}

// ---------------- K1: partial sums (sum, sumsq) of h1 columns over batch ----
// 64 blocks x 256 threads, each thread exactly one float2 of x.
__global__ __launch_bounds__(256) void k_part1(const float* __restrict__ x,
        const float* __restrict__ w1, const float* __restrict__ b1,
        float* __restrict__ p1, int B) {
    float w1r[16], b1r[16], s[16], q[16];
#pragma unroll
    for (int j = 0; j < 16; ++j) { w1r[j] = w1[j]; b1r[j] = b1[j]; s[j] = 0.f; q[j] = 0.f; }
    int tid = threadIdx.x;
    int i = blockIdx.x * 256 + tid;
    if (2 * i < B) {
        f32x2 xv = *(const f32x2*)(x + 2 * i);
#pragma unroll
        for (int e = 0; e < 2; ++e) {
#pragma unroll
            for (int j = 0; j < 16; ++j) {
                float h = leaky(fmaf(xv[e], w1r[j], b1r[j]));
                s[j] += h; q[j] += h * h;
            }
        }
    }
#pragma unroll
    for (int j = 0; j < 16; ++j) {
        for (int off = 32; off >= 1; off >>= 1) {
            s[j] += __shfl_xor(s[j], off, 64);
            q[j] += __shfl_xor(q[j], off, 64);
        }
    }
    __shared__ float red[4][32];
    int w = tid >> 6, lane = tid & 63;
    if (lane == 0) {
#pragma unroll
        for (int j = 0; j < 16; ++j) { red[w][j] = s[j]; red[w][j + 16] = q[j]; }
    }
    __syncthreads();
    if (tid < 32)
        p1[blockIdx.x * 32 + tid] = red[0][tid] + red[1][tid] + red[2][tid] + red[3][tid];
}

// Wave0 helper: fold BN1 + Linear2 into coef[0..15]=a[j], coef[16]=c0.
__device__ __forceinline__ void fold_bn1(const float* __restrict__ p1,
        const float* __restrict__ w2, const float* __restrict__ b2,
        const float* __restrict__ g1, const float* __restrict__ be1,
        float* coef, int tid, float invB) {
    float acc = 0.f;
    for (int i = 0; i < 64; ++i) acc += p1[i * 32 + tid];
    float qacc = __shfl(acc, tid + 16, 64);   // lanes 0..15 fetch sumsq
    float cp = 0.f;
    if (tid < 16) {
        float mean = acc * invB;
        float var  = qacc * invB - mean * mean;
        float inv  = rsqrtf(var + BN_EPS) * g1[tid];
        float sh   = fmaf(-mean, inv, be1[tid]);
        coef[tid] = inv * w2[tid];
        cp = sh * w2[tid];
    }
    for (int off = 8; off >= 1; off >>= 1) cp += __shfl_xor(cp, off, 16);
    if (tid == 0) coef[16] = cp + b2[0];
}

// -------- K2: fold BN1 (block0 publishes coef to ws) + h2 stats partials ---
__global__ __launch_bounds__(256) void k_h2f(const float* __restrict__ x,
        const float* __restrict__ w1, const float* __restrict__ b1,
        const float* __restrict__ p1, const float* __restrict__ w2,
        const float* __restrict__ b2, const float* __restrict__ g1,
        const float* __restrict__ be1, float* __restrict__ p2,
        float* __restrict__ cfws, int B, float invB) {
    __shared__ float coef[17];
    int tid = threadIdx.x;
    if (tid < 32) fold_bn1(p1, w2, b2, g1, be1, coef, tid, invB);
    __syncthreads();
    if (blockIdx.x == 0 && tid < 17) cfws[tid] = coef[tid];
    float w1r[16], b1r[16], ar[16];
#pragma unroll
    for (int j = 0; j < 16; ++j) { w1r[j] = w1[j]; b1r[j] = b1[j]; ar[j] = coef[j]; }
    float c0 = coef[16];
    float s = 0.f, q = 0.f;
    int i = blockIdx.x * 256 + tid;
    if (2 * i < B) {
        f32x2 xv = *(const f32x2*)(x + 2 * i);
#pragma unroll
        for (int e = 0; e < 2; ++e) {
            float acc = c0;
#pragma unroll
            for (int j = 0; j < 16; ++j) {
                float h = leaky(fmaf(xv[e], w1r[j], b1r[j]));
                acc = fmaf(h, ar[j], acc);
            }
            float h2 = leaky(acc);
            s += h2; q += h2 * h2;
        }
    }
    for (int off = 32; off >= 1; off >>= 1) {
        s += __shfl_xor(s, off, 64);
        q += __shfl_xor(q, off, 64);
    }
    __shared__ float red[4][2];
    int w = tid >> 6, lane = tid & 63;
    if (lane == 0) { red[w][0] = s; red[w][1] = q; }
    __syncthreads();
    if (tid == 0) {
        p2[blockIdx.x * 2 + 0] = red[0][0] + red[1][0] + red[2][0] + red[3][0];
        p2[blockIdx.x * 2 + 1] = red[0][1] + red[1][1] + red[2][1] + red[3][1];
    }
}

// ---------------- K3: register tree, 32 rows/block, BN2 folded into weights
// Store structure identical to R3 (lane-contiguous dwordx4 NT for levels>=8).
__global__ __launch_bounds__(256) void k_tree(const float* __restrict__ x,
        const float* __restrict__ w1, const float* __restrict__ b1,
        const float* __restrict__ g2, const float* __restrict__ be2,
        const float* __restrict__ fcw, const float* __restrict__ fcb,
        const float* __restrict__ p2, const float* __restrict__ cfws,
        float* __restrict__ out, int B, float invB) {
    __shared__ float wl[1024], bl[1024];
    __shared__ float x2s[32];      // h2 per block-row
    __shared__ float bn2[2];       // s2, t2
    int tid = threadIdx.x;

    // Stage fc weights raw, swizzled slot-major (same map as R3).
    for (int i = tid; i < 1024; i += 256) {
        int d;
        if (i < 128)      d = i;
        else if (i < 256) { int o = i - 128; d = 128 + ((o & 1) << 6) + (o >> 1); }
        else if (i < 512) { int o = i - 256; d = 256 + ((((o >> 7) << 1) | (o & 1)) << 6) + ((o & 127) >> 1); }
        else              { int o = i - 512; d = 512 + ((((o >> 7) << 1) | (o & 1)) << 6) + ((o & 127) >> 1); }
        wl[d] = fcw[i];
        bl[d] = fcb[i];
    }
    // Parallel BN2 stats reduce (64 partial pairs)
    if (tid < 64) {
        float s = p2[2 * tid], q = p2[2 * tid + 1];
        for (int off = 32; off >= 1; off >>= 1) {
            s += __shfl_xor(s, off, 64);
            q += __shfl_xor(q, off, 64);
        }
        if (tid == 0) {
            float mean = s * invB, var = q * invB - mean * mean;
            float inv = rsqrtf(var + BN_EPS) * g2[0];
            bn2[0] = inv;
            bn2[1] = fmaf(-mean, inv, be2[0]);
        }
    }
    __syncthreads();
    // Fold BN2 into weights: z*log2e = h2*(s2*w*log2e) + (t2*w + b)*log2e
    {
        float s2k = bn2[0] * LOG2E, t2 = bn2[1];
        for (int i = tid; i < 1024; i += 256) {
            float wv = wl[i];
            wl[i] = wv * s2k;
            bl[i] = fmaf(t2, wv, bl[i]) * LOG2E;
        }
    }
    // h2 per block-row (32 rows), from x via published coef
    if (tid < 32) {
        int r = blockIdx.x * 32 + tid;
        float xv = (r < B) ? x[r] : 0.f;
        float acc = cfws[16];
#pragma unroll
        for (int j = 0; j < 16; ++j) {
            float h = leaky(fmaf(xv, w1[j], b1[j]));
            acc = fmaf(h, cfws[j], acc);
        }
        x2s[tid] = leaky(acc);
    }
    __syncthreads();

    const int w = tid >> 6, lane = tid & 63;
    // 4 row-pair iterations per wave: rows rbase .. rbase+7
    const int rbase = blockIdx.x * 32 + w * 8;
    for (int rp = 0; rp < 4; ++rp) {
        const int r0 = rbase + 2 * rp;
        float x2[2]; bool act[2]; float* op[2];
#pragma unroll
        for (int rr = 0; rr < 2; ++rr) {
            x2[rr] = x2s[w * 8 + 2 * rp + rr];
            act[rr] = (r0 + rr) < B;
            op[rr] = out + (size_t)(r0 + rr) * 2048;
            if (act[rr] && lane == 0) st2(op[rr], 0.f, 1.f);
        }

        float mup[2] = {1.f, 1.f};
        // ---- levels 1..6: shuffle levels ----
#pragma unroll
        for (int l = 1; l <= 6; ++l) {
            const int P = 1 << (l - 1);
            float wv = wl[P + lane], bv = bl[P + lane];
#pragma unroll
            for (int rr = 0; rr < 2; ++rr) {
                float z = fmaf(x2[rr], wv, bv);
                float pz = sig2(z);
                float c0 = mup[rr] * pz, c1 = mup[rr] - c0;
                if (act[rr] && lane < P) {
                    if (l >= 5) st_nt2(op[rr] + 2 * (P + lane), c0, c1);
                    else        st2(op[rr] + 2 * (P + lane), c0, c1);
                }
                float s0 = __shfl(c0, lane >> 1, 64);
                float s1 = __shfl(c1, lane >> 1, 64);
                mup[rr] = (lane & 1) ? s1 : s0;
            }
        }
        // ---- level 7 ----
        float c2[2][2];
        {
            float wv = wl[64 + lane], bv = bl[64 + lane];
#pragma unroll
            for (int rr = 0; rr < 2; ++rr) {
                float z = fmaf(x2[rr], wv, bv);
                float pz = sig2(z);
                c2[rr][0] = mup[rr] * pz;
                c2[rr][1] = mup[rr] - c2[rr][0];
                if (act[rr]) st_nt2(op[rr] + 128 + 2 * lane, c2[rr][0], c2[rr][1]);
            }
        }
        // ---- level 8 ----
        float c4[2][4];
#pragma unroll
        for (int s = 0; s < 2; ++s) {
            float wv = wl[128 + (s << 6) + lane], bv = bl[128 + (s << 6) + lane];
#pragma unroll
            for (int rr = 0; rr < 2; ++rr) {
                float z = fmaf(x2[rr], wv, bv);
                float pz = sig2(z);
                c4[rr][2 * s]     = c2[rr][s] * pz;
                c4[rr][2 * s + 1] = c2[rr][s] - c4[rr][2 * s];
            }
        }
#pragma unroll
        for (int rr = 0; rr < 2; ++rr)
            if (act[rr])
                st_nt4(op[rr] + 256 + (lane << 2), c4[rr][0], c4[rr][1], c4[rr][2], c4[rr][3]);
        // ---- level 9 ----
        float c8[2][2][4];
#pragma unroll
        for (int j2 = 0; j2 < 2; ++j2) {
            int src = (j2 << 5) + (lane >> 1);
            float wv0 = wl[256 + ((2 * j2) << 6) + lane],     bv0 = bl[256 + ((2 * j2) << 6) + lane];
            float wv1 = wl[256 + ((2 * j2 + 1) << 6) + lane], bv1 = bl[256 + ((2 * j2 + 1) << 6) + lane];
#pragma unroll
            for (int rr = 0; rr < 2; ++rr) {
                float A  = __shfl(c4[rr][0], src, 64);
                float Bv = __shfl(c4[rr][1], src, 64);
                float C  = __shfl(c4[rr][2], src, 64);
                float D  = __shfl(c4[rr][3], src, 64);
                float m0 = (lane & 1) ? C : A;
                float m1 = (lane & 1) ? D : Bv;
                float z0 = fmaf(x2[rr], wv0, bv0);
                float z1 = fmaf(x2[rr], wv1, bv1);
                float p0 = sig2(z0), p1v = sig2(z1);
                c8[rr][j2][0] = m0 * p0;
                c8[rr][j2][1] = m0 - c8[rr][j2][0];
                c8[rr][j2][2] = m1 * p1v;
                c8[rr][j2][3] = m1 - c8[rr][j2][2];
                if (act[rr])
                    st_nt4(op[rr] + 512 + (j2 << 8) + (lane << 2),
                           c8[rr][j2][0], c8[rr][j2][1], c8[rr][j2][2], c8[rr][j2][3]);
            }
        }
        // ---- level 10 ----
#pragma unroll
        for (int j = 0; j < 4; ++j) {
            const int j2 = j >> 1;
            int src = ((j & 1) << 5) + (lane >> 1);
            float wv0 = wl[512 + ((2 * j) << 6) + lane],     bv0 = bl[512 + ((2 * j) << 6) + lane];
            float wv1 = wl[512 + ((2 * j + 1) << 6) + lane], bv1 = bl[512 + ((2 * j + 1) << 6) + lane];
#pragma unroll
            for (int rr = 0; rr < 2; ++rr) {
                float A  = __shfl(c8[rr][j2][0], src, 64);
                float Bv = __shfl(c8[rr][j2][1], src, 64);
                float C  = __shfl(c8[rr][j2][2], src, 64);
                float D  = __shfl(c8[rr][j2][3], src, 64);
                float m0 = (lane & 1) ? C : A;
                float m1 = (lane & 1) ? D : Bv;
                float z0 = fmaf(x2[rr], wv0, bv0);
                float z1 = fmaf(x2[rr], wv1, bv1);
                float p0 = sig2(z0), p1v = sig2(z1);
                float a0 = m0 * p0,  a1 = m0 - a0;
                float b0 = m1 * p1v, b1 = m1 - b0;
                if (act[rr])
                    st_nt4(op[rr] + 1024 + (j << 8) + (lane << 2), a0, a1, b0, b1);
            }
        }
    }
}

extern "C" void kernel_launch(void* const* d_in, const int* in_sizes, int n_in,
                              void* d_out, int out_size, void* d_ws, size_t ws_size,
                              hipStream_t stream) {
    const float* x   = (const float*)d_in[0];
    const float* w1  = (const float*)d_in[1];
    const float* b1  = (const float*)d_in[2];
    const float* g1  = (const float*)d_in[3];
    const float* be1 = (const float*)d_in[4];
    const float* w2  = (const float*)d_in[5];
    const float* b2  = (const float*)d_in[6];
    const float* g2  = (const float*)d_in[7];
    const float* be2 = (const float*)d_in[8];
    const float* fcw = (const float*)d_in[9];
    const float* fcb = (const float*)d_in[10];
    float* out = (float*)d_out;
    int B = in_sizes[0];
    float invB = 1.0f / (float)B;

    float* ws = (float*)d_ws;
    float* p1 = ws;          // 64*32 partials for BN1
    float* p2 = ws + 2048;   // 64*2 partials for BN2
    float* cf = ws + 2176;   // folded BN1+Linear2 coef [17]

    k_part1<<<64, 256, 0, stream>>>(x, w1, b1, p1, B);
    k_h2f  <<<64, 256, 0, stream>>>(x, w1, b1, p1, w2, b2, g1, be1, p2, cf, B, invB);

    int blocks = (B + 31) / 32;   // 32 rows per block (4 waves x 8 rows)
    k_tree<<<blocks, 256, 0, stream>>>(x, w1, b1, g2, be2, fcw, fcb, p2, cf,
                                       out, B, invB);
}

// Round 5
// 64.623 us; speedup vs baseline: 1.0287x; 1.0287x over previous
//
#include <hip/hip_runtime.h>

#define LEAKY_S 0.01f
#define BN_EPS 1e-5f
#define LOG2E 1.44269504088896340736f

typedef float f32x2 __attribute__((ext_vector_type(2)));
typedef float f32x4 __attribute__((ext_vector_type(4)));

__device__ __forceinline__ float leaky(float v) { return v >= 0.0f ? v : LEAKY_S * v; }
__device__ __forceinline__ float fast_exp2(float v) { return __builtin_amdgcn_exp2f(v); }
// sigmoid(z) with weights pre-scaled by log2e
__device__ __forceinline__ float sig2(float z2) {
    return __builtin_amdgcn_rcpf(1.0f + fast_exp2(-z2));
}
__device__ __forceinline__ void st2(float* p, float a, float b) {
    f32x2 v = {a, b}; *(f32x2*)p = v;
}
__device__ __forceinline__ void st_nt2(float* p, float a, float b) {
    f32x2 v = {a, b}; __builtin_nontemporal_store(v, (f32x2*)p);
}
__device__ __forceinline__ void st_nt4(float* p, float a, float b, float c, float d) {
    f32x4 v = {a, b, c, d}; __builtin_nontemporal_store(v, (f32x4*)p);
}

// ---------------- K1: partial sums (sum, sumsq) of h1 columns over batch ----
// 64 blocks x 256 threads, each thread exactly one float2 of x.
__global__ __launch_bounds__(256) void k_part1(const float* __restrict__ x,
        const float* __restrict__ w1, const float* __restrict__ b1,
        float* __restrict__ p1, int B) {
    float w1r[16], b1r[16], s[16], q[16];
#pragma unroll
    for (int j = 0; j < 16; ++j) { w1r[j] = w1[j]; b1r[j] = b1[j]; s[j] = 0.f; q[j] = 0.f; }
    int tid = threadIdx.x;
    int i = blockIdx.x * 256 + tid;
    if (2 * i < B) {
        f32x2 xv = *(const f32x2*)(x + 2 * i);
#pragma unroll
        for (int e = 0; e < 2; ++e) {
#pragma unroll
            for (int j = 0; j < 16; ++j) {
                float h = leaky(fmaf(xv[e], w1r[j], b1r[j]));
                s[j] += h; q[j] += h * h;
            }
        }
    }
#pragma unroll
    for (int j = 0; j < 16; ++j) {
        for (int off = 32; off >= 1; off >>= 1) {
            s[j] += __shfl_xor(s[j], off, 64);
            q[j] += __shfl_xor(q[j], off, 64);
        }
    }
    __shared__ float red[4][32];
    int w = tid >> 6, lane = tid & 63;
    if (lane == 0) {
#pragma unroll
        for (int j = 0; j < 16; ++j) { red[w][j] = s[j]; red[w][j + 16] = q[j]; }
    }
    __syncthreads();
    if (tid < 32)
        p1[blockIdx.x * 32 + tid] = red[0][tid] + red[1][tid] + red[2][tid] + red[3][tid];
}

// Wave0 helper: fold BN1 + Linear2 into coef[0..15]=a[j], coef[16]=c0.
__device__ __forceinline__ void fold_bn1(const float* __restrict__ p1,
        const float* __restrict__ w2, const float* __restrict__ b2,
        const float* __restrict__ g1, const float* __restrict__ be1,
        float* coef, int tid, float invB) {
    float acc = 0.f;
    for (int i = 0; i < 64; ++i) acc += p1[i * 32 + tid];
    float qacc = __shfl(acc, tid + 16, 64);   // lanes 0..15 fetch sumsq
    float cp = 0.f;
    if (tid < 16) {
        float mean = acc * invB;
        float var  = qacc * invB - mean * mean;
        float inv  = rsqrtf(var + BN_EPS) * g1[tid];
        float sh   = fmaf(-mean, inv, be1[tid]);
        coef[tid] = inv * w2[tid];
        cp = sh * w2[tid];
    }
    for (int off = 8; off >= 1; off >>= 1) cp += __shfl_xor(cp, off, 16);
    if (tid == 0) coef[16] = cp + b2[0];
}

// -------- K2: fold BN1 (block0 publishes coef to ws) + h2 stats partials ---
__global__ __launch_bounds__(256) void k_h2f(const float* __restrict__ x,
        const float* __restrict__ w1, const float* __restrict__ b1,
        const float* __restrict__ p1, const float* __restrict__ w2,
        const float* __restrict__ b2, const float* __restrict__ g1,
        const float* __restrict__ be1, float* __restrict__ p2,
        float* __restrict__ cfws, int B, float invB) {
    __shared__ float coef[17];
    int tid = threadIdx.x;
    if (tid < 32) fold_bn1(p1, w2, b2, g1, be1, coef, tid, invB);
    __syncthreads();
    if (blockIdx.x == 0 && tid < 17) cfws[tid] = coef[tid];
    float w1r[16], b1r[16], ar[16];
#pragma unroll
    for (int j = 0; j < 16; ++j) { w1r[j] = w1[j]; b1r[j] = b1[j]; ar[j] = coef[j]; }
    float c0 = coef[16];
    float s = 0.f, q = 0.f;
    int i = blockIdx.x * 256 + tid;
    if (2 * i < B) {
        f32x2 xv = *(const f32x2*)(x + 2 * i);
#pragma unroll
        for (int e = 0; e < 2; ++e) {
            float acc = c0;
#pragma unroll
            for (int j = 0; j < 16; ++j) {
                float h = leaky(fmaf(xv[e], w1r[j], b1r[j]));
                acc = fmaf(h, ar[j], acc);
            }
            float h2 = leaky(acc);
            s += h2; q += h2 * h2;
        }
    }
    for (int off = 32; off >= 1; off >>= 1) {
        s += __shfl_xor(s, off, 64);
        q += __shfl_xor(q, off, 64);
    }
    __shared__ float red[4][2];
    int w = tid >> 6, lane = tid & 63;
    if (lane == 0) { red[w][0] = s; red[w][1] = q; }
    __syncthreads();
    if (tid == 0) {
        p2[blockIdx.x * 2 + 0] = red[0][0] + red[1][0] + red[2][0] + red[3][0];
        p2[blockIdx.x * 2 + 1] = red[0][1] + red[1][1] + red[2][1] + red[3][1];
    }
}

// ---------------- K3: register tree, ONE row per wave (4 rows/block) -------
// Each wave's stores walk one 8 KB row in strictly increasing addresses.
// Deep levels (>=8) are lane-contiguous dwordx4 NT stores (R3's proven
// layout). Light prologue: staged+swizzled weights with BN2 folded in.
__global__ __launch_bounds__(256) void k_tree(const float* __restrict__ x,
        const float* __restrict__ w1, const float* __restrict__ b1,
        const float* __restrict__ g2, const float* __restrict__ be2,
        const float* __restrict__ fcw, const float* __restrict__ fcb,
        const float* __restrict__ p2, const float* __restrict__ cfws,
        float* __restrict__ out, int B, float invB) {
    __shared__ float wl[1024], bl[1024];
    __shared__ float x2s[4];       // h2 per block-row
    __shared__ float bn2[2];       // s2, t2
    int tid = threadIdx.x;

    // Stage fc weights raw, swizzled slot-major (same map as R3).
    for (int i = tid; i < 1024; i += 256) {
        int d;
        if (i < 128)      d = i;
        else if (i < 256) { int o = i - 128; d = 128 + ((o & 1) << 6) + (o >> 1); }
        else if (i < 512) { int o = i - 256; d = 256 + ((((o >> 7) << 1) | (o & 1)) << 6) + ((o & 127) >> 1); }
        else              { int o = i - 512; d = 512 + ((((o >> 7) << 1) | (o & 1)) << 6) + ((o & 127) >> 1); }
        wl[d] = fcw[i];
        bl[d] = fcb[i];
    }
    // Wave0: parallel BN2 stats reduce (64 partial pairs)
    if (tid < 64) {
        float s = p2[2 * tid], q = p2[2 * tid + 1];
        for (int off = 32; off >= 1; off >>= 1) {
            s += __shfl_xor(s, off, 64);
            q += __shfl_xor(q, off, 64);
        }
        if (tid == 0) {
            float mean = s * invB, var = q * invB - mean * mean;
            float inv = rsqrtf(var + BN_EPS) * g2[0];
            bn2[0] = inv;
            bn2[1] = fmaf(-mean, inv, be2[0]);
        }
    }
    // Wave1 lanes 0..3: h2 for this block's 4 rows (pre-BN2; BN2 is in weights)
    if (tid >= 64 && tid < 68) {
        int rr = tid - 64;
        int r = blockIdx.x * 4 + rr;
        float xv = (r < B) ? x[r] : 0.f;
        float acc = cfws[16];
#pragma unroll
        for (int j = 0; j < 16; ++j) {
            float h = leaky(fmaf(xv, w1[j], b1[j]));
            acc = fmaf(h, cfws[j], acc);
        }
        x2s[rr] = leaky(acc);
    }
    __syncthreads();
    // Fold BN2 into weights: z*log2e = h2*(s2*w*log2e) + (t2*w + b)*log2e
    {
        float s2k = bn2[0] * LOG2E, t2 = bn2[1];
        for (int i = tid; i < 1024; i += 256) {
            float wv = wl[i];
            wl[i] = wv * s2k;
            bl[i] = fmaf(t2, wv, bl[i]) * LOG2E;
        }
    }
    __syncthreads();

    const int w = tid >> 6, lane = tid & 63;
    const int r = blockIdx.x * 4 + w;
    const bool act = r < B;              // wave-uniform
    const float x2 = x2s[w];
    float* op = out + (size_t)r * 2048;
    if (act && lane == 0) st2(op, 0.f, 1.f);

    float mup = 1.f;
    // ---- levels 1..6: shuffle levels ----
#pragma unroll
    for (int l = 1; l <= 6; ++l) {
        const int P = 1 << (l - 1);
        float wv = wl[P + lane], bv = bl[P + lane];
        float z = fmaf(x2, wv, bv);
        float pz = sig2(z);
        float c0 = mup * pz, c1 = mup - c0;
        if (act && lane < P) {
            if (l >= 5) st_nt2(op + 2 * (P + lane), c0, c1);
            else        st2(op + 2 * (P + lane), c0, c1);
        }
        float s0 = __shfl(c0, lane >> 1, 64);
        float s1 = __shfl(c1, lane >> 1, 64);
        mup = (lane & 1) ? s1 : s0;
    }
    // ---- level 7: parent 64+lane, children stay in-lane ----
    float c2v[2];
    {
        float wv = wl[64 + lane], bv = bl[64 + lane];
        float z = fmaf(x2, wv, bv);
        float pz = sig2(z);
        c2v[0] = mup * pz;
        c2v[1] = mup - c2v[0];
        if (act) st_nt2(op + 128 + 2 * lane, c2v[0], c2v[1]);
    }
    // ---- level 8: parents {128+2i, 128+2i+1}; mus in-lane (c2v) ----
    float c4v[4];
#pragma unroll
    for (int s = 0; s < 2; ++s) {
        float wv = wl[128 + (s << 6) + lane], bv = bl[128 + (s << 6) + lane];
        float z = fmaf(x2, wv, bv);
        float pz = sig2(z);
        c4v[2 * s]     = c2v[s] * pz;
        c4v[2 * s + 1] = c2v[s] - c4v[2 * s];
    }
    if (act)
        st_nt4(op + 256 + (lane << 2), c4v[0], c4v[1], c4v[2], c4v[3]);
    // ---- level 9: parents {256 + j2*128 + 2i + s}; mus from lane j2*32+(i>>1)
    float c8v[2][4];
#pragma unroll
    for (int j2 = 0; j2 < 2; ++j2) {
        int src = (j2 << 5) + (lane >> 1);
        float A  = __shfl(c4v[0], src, 64);
        float Bv = __shfl(c4v[1], src, 64);
        float C  = __shfl(c4v[2], src, 64);
        float D  = __shfl(c4v[3], src, 64);
        float m0 = (lane & 1) ? C : A;
        float m1 = (lane & 1) ? D : Bv;
        float wv0 = wl[256 + ((2 * j2) << 6) + lane],     bv0 = bl[256 + ((2 * j2) << 6) + lane];
        float wv1 = wl[256 + ((2 * j2 + 1) << 6) + lane], bv1 = bl[256 + ((2 * j2 + 1) << 6) + lane];
        float z0 = fmaf(x2, wv0, bv0);
        float z1 = fmaf(x2, wv1, bv1);
        float p0 = sig2(z0), p1v = sig2(z1);
        c8v[j2][0] = m0 * p0;
        c8v[j2][1] = m0 - c8v[j2][0];
        c8v[j2][2] = m1 * p1v;
        c8v[j2][3] = m1 - c8v[j2][2];
        if (act)
            st_nt4(op + 512 + (j2 << 8) + (lane << 2),
                   c8v[j2][0], c8v[j2][1], c8v[j2][2], c8v[j2][3]);
    }
    // ---- level 10: parents {512 + j*128 + 2i + s}; mus from lane (j&1)*32+(i>>1)
#pragma unroll
    for (int j = 0; j < 4; ++j) {
        const int j2 = j >> 1;
        int src = ((j & 1) << 5) + (lane >> 1);
        float A  = __shfl(c8v[j2][0], src, 64);
        float Bv = __shfl(c8v[j2][1], src, 64);
        float C  = __shfl(c8v[j2][2], src, 64);
        float D  = __shfl(c8v[j2][3], src, 64);
        float m0 = (lane & 1) ? C : A;
        float m1 = (lane & 1) ? D : Bv;
        float wv0 = wl[512 + ((2 * j) << 6) + lane],     bv0 = bl[512 + ((2 * j) << 6) + lane];
        float wv1 = wl[512 + ((2 * j + 1) << 6) + lane], bv1 = bl[512 + ((2 * j + 1) << 6) + lane];
        float z0 = fmaf(x2, wv0, bv0);
        float z1 = fmaf(x2, wv1, bv1);
        float p0 = sig2(z0), p1v = sig2(z1);
        float a0 = m0 * p0,  a1 = m0 - a0;
        float b0 = m1 * p1v, b1 = m1 - b0;
        if (act)
            st_nt4(op + 1024 + (j << 8) + (lane << 2), a0, a1, b0, b1);
    }
}

extern "C" void kernel_launch(void* const* d_in, const int* in_sizes, int n_in,
                              void* d_out, int out_size, void* d_ws, size_t ws_size,
                              hipStream_t stream) {
    const float* x   = (const float*)d_in[0];
    const float* w1  = (const float*)d_in[1];
    const float* b1  = (const float*)d_in[2];
    const float* g1  = (const float*)d_in[3];
    const float* be1 = (const float*)d_in[4];
    const float* w2  = (const float*)d_in[5];
    const float* b2  = (const float*)d_in[6];
    const float* g2  = (const float*)d_in[7];
    const float* be2 = (const float*)d_in[8];
    const float* fcw = (const float*)d_in[9];
    const float* fcb = (const float*)d_in[10];
    float* out = (float*)d_out;
    int B = in_sizes[0];
    float invB = 1.0f / (float)B;

    float* ws = (float*)d_ws;
    float* p1 = ws;          // 64*32 partials for BN1
    float* p2 = ws + 2048;   // 64*2 partials for BN2
    float* cf = ws + 2176;   // folded BN1+Linear2 coef [17]

    k_part1<<<64, 256, 0, stream>>>(x, w1, b1, p1, B);
    k_h2f  <<<64, 256, 0, stream>>>(x, w1, b1, p1, w2, b2, g1, be1, p2, cf, B, invB);

    int blocks = (B + 3) / 4;   // 4 rows per block, 1 row per wave
    k_tree<<<blocks, 256, 0, stream>>>(x, w1, b1, g2, be2, fcw, fcb, p2, cf,
                                       out, B, invB);
}

// Round 6
// 64.278 us; speedup vs baseline: 1.0342x; 1.0054x over previous
//
#include <hip/hip_runtime.h>

#define LEAKY_S 0.01f
#define BN_EPS 1e-5f
#define LOG2E 1.44269504088896340736f

typedef float f32x2 __attribute__((ext_vector_type(2)));
typedef float f32x4 __attribute__((ext_vector_type(4)));

__device__ __forceinline__ float leaky(float v) { return v >= 0.0f ? v : LEAKY_S * v; }
__device__ __forceinline__ float fast_exp2(float v) { return __builtin_amdgcn_exp2f(v); }
// sigmoid(z) with weights pre-scaled by log2e
__device__ __forceinline__ float sig2(float z2) {
    return __builtin_amdgcn_rcpf(1.0f + fast_exp2(-z2));
}
__device__ __forceinline__ void st_nt4(float* p, float a, float b, float c, float d) {
    f32x4 v = {a, b, c, d}; __builtin_nontemporal_store(v, (f32x4*)p);
}

// ---------------- K1: partial sums (sum, sumsq) of h1 columns over batch ----
__global__ __launch_bounds__(256) void k_part1(const float* __restrict__ x,
        const float* __restrict__ w1, const float* __restrict__ b1,
        float* __restrict__ p1, int B) {
    float w1r[16], b1r[16], s[16], q[16];
#pragma unroll
    for (int j = 0; j < 16; ++j) { w1r[j] = w1[j]; b1r[j] = b1[j]; s[j] = 0.f; q[j] = 0.f; }
    int tid = threadIdx.x;
    int i = blockIdx.x * 256 + tid;
    if (2 * i < B) {
        f32x2 xv = *(const f32x2*)(x + 2 * i);
#pragma unroll
        for (int e = 0; e < 2; ++e) {
#pragma unroll
            for (int j = 0; j < 16; ++j) {
                float h = leaky(fmaf(xv[e], w1r[j], b1r[j]));
                s[j] += h; q[j] += h * h;
            }
        }
    }
#pragma unroll
    for (int j = 0; j < 16; ++j) {
        for (int off = 32; off >= 1; off >>= 1) {
            s[j] += __shfl_xor(s[j], off, 64);
            q[j] += __shfl_xor(q[j], off, 64);
        }
    }
    __shared__ float red[4][32];
    int w = tid >> 6, lane = tid & 63;
    if (lane == 0) {
#pragma unroll
        for (int j = 0; j < 16; ++j) { red[w][j] = s[j]; red[w][j + 16] = q[j]; }
    }
    __syncthreads();
    if (tid < 32)
        p1[blockIdx.x * 32 + tid] = red[0][tid] + red[1][tid] + red[2][tid] + red[3][tid];
}

// Wave0 helper: fold BN1 + Linear2 into coef[0..15]=a[j], coef[16]=c0.
__device__ __forceinline__ void fold_bn1(const float* __restrict__ p1,
        const float* __restrict__ w2, const float* __restrict__ b2,
        const float* __restrict__ g1, const float* __restrict__ be1,
        float* coef, int tid, float invB) {
    float acc = 0.f;
    for (int i = 0; i < 64; ++i) acc += p1[i * 32 + tid];
    float qacc = __shfl(acc, tid + 16, 64);   // lanes 0..15 fetch sumsq
    float cp = 0.f;
    if (tid < 16) {
        float mean = acc * invB;
        float var  = qacc * invB - mean * mean;
        float inv  = rsqrtf(var + BN_EPS) * g1[tid];
        float sh   = fmaf(-mean, inv, be1[tid]);
        coef[tid] = inv * w2[tid];
        cp = sh * w2[tid];
    }
    for (int off = 8; off >= 1; off >>= 1) cp += __shfl_xor(cp, off, 16);
    if (tid == 0) coef[16] = cp + b2[0];
}

// -------- K2: fold BN1 (block0 publishes coef to ws) + h2 stats partials ---
__global__ __launch_bounds__(256) void k_h2f(const float* __restrict__ x,
        const float* __restrict__ w1, const float* __restrict__ b1,
        const float* __restrict__ p1, const float* __restrict__ w2,
        const float* __restrict__ b2, const float* __restrict__ g1,
        const float* __restrict__ be1, float* __restrict__ p2,
        float* __restrict__ cfws, int B, float invB) {
    __shared__ float coef[17];
    int tid = threadIdx.x;
    if (tid < 32) fold_bn1(p1, w2, b2, g1, be1, coef, tid, invB);
    __syncthreads();
    if (blockIdx.x == 0 && tid < 17) cfws[tid] = coef[tid];
    float w1r[16], b1r[16], ar[16];
#pragma unroll
    for (int j = 0; j < 16; ++j) { w1r[j] = w1[j]; b1r[j] = b1[j]; ar[j] = coef[j]; }
    float c0 = coef[16];
    float s = 0.f, q = 0.f;
    int i = blockIdx.x * 256 + tid;
    if (2 * i < B) {
        f32x2 xv = *(const f32x2*)(x + 2 * i);
#pragma unroll
        for (int e = 0; e < 2; ++e) {
            float acc = c0;
#pragma unroll
            for (int j = 0; j < 16; ++j) {
                float h = leaky(fmaf(xv[e], w1r[j], b1r[j]));
                acc = fmaf(h, ar[j], acc);
            }
            float h2 = leaky(acc);
            s += h2; q += h2 * h2;
        }
    }
    for (int off = 32; off >= 1; off >>= 1) {
        s += __shfl_xor(s, off, 64);
        q += __shfl_xor(q, off, 64);
    }
    __shared__ float red[4][2];
    int w = tid >> 6, lane = tid & 63;
    if (lane == 0) { red[w][0] = s; red[w][1] = q; }
    __syncthreads();
    if (tid == 0) {
        p2[blockIdx.x * 2 + 0] = red[0][0] + red[1][0] + red[2][0] + red[3][0];
        p2[blockIdx.x * 2 + 1] = red[0][1] + red[1][1] + red[2][1] + red[3][1];
    }
}

// ---------------- K3: register tree, 1 row/wave, WHOLE ROW IN REGISTERS ----
// All 2048 row values land in 32 regs/lane (lane i holds floats 4i..4i+3 of
// each 256-float segment); the row is then emitted as 8 back-to-back
// lane-contiguous dwordx4 NT stores — fillBuffer's exact store pattern.
__global__ __launch_bounds__(256) void k_tree(const float* __restrict__ x,
        const float* __restrict__ w1, const float* __restrict__ b1,
        const float* __restrict__ g2, const float* __restrict__ be2,
        const float* __restrict__ fcw, const float* __restrict__ fcb,
        const float* __restrict__ p2, const float* __restrict__ cfws,
        float* __restrict__ out, int B, float invB) {
    __shared__ float wl[1024], bl[1024];
    __shared__ float x2s[4];       // h2 per block-row
    __shared__ float bn2[2];       // s2, t2
    int tid = threadIdx.x;

    // Stage fc weights raw, swizzled slot-major (same map as R3).
    for (int i = tid; i < 1024; i += 256) {
        int d;
        if (i < 128)      d = i;
        else if (i < 256) { int o = i - 128; d = 128 + ((o & 1) << 6) + (o >> 1); }
        else if (i < 512) { int o = i - 256; d = 256 + ((((o >> 7) << 1) | (o & 1)) << 6) + ((o & 127) >> 1); }
        else              { int o = i - 512; d = 512 + ((((o >> 7) << 1) | (o & 1)) << 6) + ((o & 127) >> 1); }
        wl[d] = fcw[i];
        bl[d] = fcb[i];
    }
    // Wave0: parallel BN2 stats reduce (64 partial pairs)
    if (tid < 64) {
        float s = p2[2 * tid], q = p2[2 * tid + 1];
        for (int off = 32; off >= 1; off >>= 1) {
            s += __shfl_xor(s, off, 64);
            q += __shfl_xor(q, off, 64);
        }
        if (tid == 0) {
            float mean = s * invB, var = q * invB - mean * mean;
            float inv = rsqrtf(var + BN_EPS) * g2[0];
            bn2[0] = inv;
            bn2[1] = fmaf(-mean, inv, be2[0]);
        }
    }
    // Wave1 lanes 0..3: h2 for this block's 4 rows (pre-BN2; BN2 in weights)
    if (tid >= 64 && tid < 68) {
        int rr = tid - 64;
        int r = blockIdx.x * 4 + rr;
        float xv = (r < B) ? x[r] : 0.f;
        float acc = cfws[16];
#pragma unroll
        for (int j = 0; j < 16; ++j) {
            float h = leaky(fmaf(xv, w1[j], b1[j]));
            acc = fmaf(h, cfws[j], acc);
        }
        x2s[rr] = leaky(acc);
    }
    __syncthreads();
    // Fold BN2 into weights: z*log2e = h2*(s2*w*log2e) + (t2*w + b)*log2e
    {
        float s2k = bn2[0] * LOG2E, t2 = bn2[1];
        for (int i = tid; i < 1024; i += 256) {
            float wv = wl[i];
            wl[i] = wv * s2k;
            bl[i] = fmaf(t2, wv, bl[i]) * LOG2E;
        }
    }
    __syncthreads();

    const int w = tid >> 6, lane = tid & 63;
    const int r = blockIdx.x * 4 + w;
    const bool act = r < B;              // wave-uniform
    const float x2 = x2s[w];
    float* op = out + (size_t)r * 2048;

    float s0q[4];                        // segment 0: floats 4*lane .. +3
    float mup;
    // ---- level 1 (uniform across lanes; no shuffle needed) ----
    {
        float z = fmaf(x2, wl[1], bl[1]);
        float pz = sig2(z);
        float c0 = pz, c1 = 1.0f - pz;   // mu parent = 1
        if (lane == 0) { s0q[0] = 0.f; s0q[1] = 1.f; s0q[2] = c0; s0q[3] = c1; }
        mup = (lane & 1) ? c1 : c0;
    }
    // ---- levels 2..6: shuffle levels; gather children into seg0 ----
#pragma unroll
    for (int l = 2; l <= 6; ++l) {
        const int P = 1 << (l - 1);
        float wv = wl[P + lane], bv = bl[P + lane];
        float z = fmaf(x2, wv, bv);
        float pz = sig2(z);
        float c0 = mup * pz, c1 = mup - c0;     // valid in lanes < P
        int sk = (2 * lane - P) & 63;
        float g0 = __shfl(c0, sk, 64);
        float g1 = __shfl(c1, sk, 64);
        float g2 = __shfl(c0, sk + 1, 64);
        float g3 = __shfl(c1, sk + 1, 64);
        if (lane >= P / 2 && lane < P) { s0q[0] = g0; s0q[1] = g1; s0q[2] = g2; s0q[3] = g3; }
        float n0 = __shfl(c0, lane >> 1, 64);
        float n1 = __shfl(c1, lane >> 1, 64);
        mup = (lane & 1) ? n1 : n0;
    }
    // ---- level 7: parent 64+lane; children stay in-lane + gather seg0 ----
    float c2v[2];
    {
        float wv = wl[64 + lane], bv = bl[64 + lane];
        float z = fmaf(x2, wv, bv);
        float pz = sig2(z);
        c2v[0] = mup * pz;
        c2v[1] = mup - c2v[0];
        int sk = (2 * lane - 64) & 63;
        float g0 = __shfl(c2v[0], sk, 64);
        float g1 = __shfl(c2v[1], sk, 64);
        float g2 = __shfl(c2v[0], sk + 1, 64);
        float g3 = __shfl(c2v[1], sk + 1, 64);
        if (lane >= 32) { s0q[0] = g0; s0q[1] = g1; s0q[2] = g2; s0q[3] = g3; }
    }
    // ---- level 8: parents {128+2i, 128+2i+1}; mus in-lane (c2v) ----
    float c4v[4];
#pragma unroll
    for (int s = 0; s < 2; ++s) {
        float wv = wl[128 + (s << 6) + lane], bv = bl[128 + (s << 6) + lane];
        float z = fmaf(x2, wv, bv);
        float pz = sig2(z);
        c4v[2 * s]     = c2v[s] * pz;
        c4v[2 * s + 1] = c2v[s] - c4v[2 * s];
    }
    // ---- level 9: parents {256 + j2*128 + 2i + s}; mus from lane j2*32+(i>>1)
    float c8v[2][4];
#pragma unroll
    for (int j2 = 0; j2 < 2; ++j2) {
        int src = (j2 << 5) + (lane >> 1);
        float A  = __shfl(c4v[0], src, 64);
        float Bv = __shfl(c4v[1], src, 64);
        float C  = __shfl(c4v[2], src, 64);
        float D  = __shfl(c4v[3], src, 64);
        float m0 = (lane & 1) ? C : A;
        float m1 = (lane & 1) ? D : Bv;
        float wv0 = wl[256 + ((2 * j2) << 6) + lane],     bv0 = bl[256 + ((2 * j2) << 6) + lane];
        float wv1 = wl[256 + ((2 * j2 + 1) << 6) + lane], bv1 = bl[256 + ((2 * j2 + 1) << 6) + lane];
        float z0 = fmaf(x2, wv0, bv0);
        float z1 = fmaf(x2, wv1, bv1);
        float p0 = sig2(z0), p1v = sig2(z1);
        c8v[j2][0] = m0 * p0;
        c8v[j2][1] = m0 - c8v[j2][0];
        c8v[j2][2] = m1 * p1v;
        c8v[j2][3] = m1 - c8v[j2][2];
    }
    // ---- level 10: parents {512 + j*128 + 2i + s}; keep results in regs ----
    float l10[4][4];
#pragma unroll
    for (int j = 0; j < 4; ++j) {
        const int j2 = j >> 1;
        int src = ((j & 1) << 5) + (lane >> 1);
        float A  = __shfl(c8v[j2][0], src, 64);
        float Bv = __shfl(c8v[j2][1], src, 64);
        float C  = __shfl(c8v[j2][2], src, 64);
        float D  = __shfl(c8v[j2][3], src, 64);
        float m0 = (lane & 1) ? C : A;
        float m1 = (lane & 1) ? D : Bv;
        float wv0 = wl[512 + ((2 * j) << 6) + lane],     bv0 = bl[512 + ((2 * j) << 6) + lane];
        float wv1 = wl[512 + ((2 * j + 1) << 6) + lane], bv1 = bl[512 + ((2 * j + 1) << 6) + lane];
        float z0 = fmaf(x2, wv0, bv0);
        float z1 = fmaf(x2, wv1, bv1);
        float p0 = sig2(z0), p1v = sig2(z1);
        l10[j][0] = m0 * p0;
        l10[j][1] = m0 - l10[j][0];
        l10[j][2] = m1 * p1v;
        l10[j][3] = m1 - l10[j][2];
    }
    // ---- burst: 8 back-to-back lane-contiguous dwordx4 NT stores ----
    if (act) {
        const int o4 = lane << 2;
        st_nt4(op + o4,        s0q[0],    s0q[1],    s0q[2],    s0q[3]);
        st_nt4(op + 256 + o4,  c4v[0],    c4v[1],    c4v[2],    c4v[3]);
        st_nt4(op + 512 + o4,  c8v[0][0], c8v[0][1], c8v[0][2], c8v[0][3]);
        st_nt4(op + 768 + o4,  c8v[1][0], c8v[1][1], c8v[1][2], c8v[1][3]);
        st_nt4(op + 1024 + o4, l10[0][0], l10[0][1], l10[0][2], l10[0][3]);
        st_nt4(op + 1280 + o4, l10[1][0], l10[1][1], l10[1][2], l10[1][3]);
        st_nt4(op + 1536 + o4, l10[2][0], l10[2][1], l10[2][2], l10[2][3]);
        st_nt4(op + 1792 + o4, l10[3][0], l10[3][1], l10[3][2], l10[3][3]);
    }
}

extern "C" void kernel_launch(void* const* d_in, const int* in_sizes, int n_in,
                              void* d_out, int out_size, void* d_ws, size_t ws_size,
                              hipStream_t stream) {
    const float* x   = (const float*)d_in[0];
    const float* w1  = (const float*)d_in[1];
    const float* b1  = (const float*)d_in[2];
    const float* g1  = (const float*)d_in[3];
    const float* be1 = (const float*)d_in[4];
    const float* w2  = (const float*)d_in[5];
    const float* b2  = (const float*)d_in[6];
    const float* g2  = (const float*)d_in[7];
    const float* be2 = (const float*)d_in[8];
    const float* fcw = (const float*)d_in[9];
    const float* fcb = (const float*)d_in[10];
    float* out = (float*)d_out;
    int B = in_sizes[0];
    float invB = 1.0f / (float)B;

    float* ws = (float*)d_ws;
    float* p1 = ws;          // 64*32 partials for BN1
    float* p2 = ws + 2048;   // 64*2 partials for BN2
    float* cf = ws + 2176;   // folded BN1+Linear2 coef [17]

    k_part1<<<64, 256, 0, stream>>>(x, w1, b1, p1, B);
    k_h2f  <<<64, 256, 0, stream>>>(x, w1, b1, p1, w2, b2, g1, be1, p2, cf, B, invB);

    int blocks = (B + 3) / 4;   // 4 rows per block, 1 row per wave
    k_tree<<<blocks, 256, 0, stream>>>(x, w1, b1, g2, be2, fcw, fcb, p2, cf,
                                       out, B, invB);
}

// Round 7
// 60.196 us; speedup vs baseline: 1.1043x; 1.0678x over previous
//
#include <hip/hip_runtime.h>

#define LEAKY_S 0.01f
#define BN_EPS 1e-5f
#define LOG2E 1.44269504088896340736f

typedef float f32x2 __attribute__((ext_vector_type(2)));
typedef float f32x4 __attribute__((ext_vector_type(4)));

__device__ __forceinline__ float leaky(float v) { return v >= 0.0f ? v : LEAKY_S * v; }
__device__ __forceinline__ float fast_exp2(float v) { return __builtin_amdgcn_exp2f(v); }
// sigmoid(z) with weights pre-scaled by log2e
__device__ __forceinline__ float sig2(float z2) {
    return __builtin_amdgcn_rcpf(1.0f + fast_exp2(-z2));
}
__device__ __forceinline__ void st4(float* p, float a, float b, float c, float d) {
    f32x4 v = {a, b, c, d}; *(f32x4*)p = v;   // cached store (A/B vs R6's NT)
}

// ---------------- K1: partial sums (sum, sumsq) of h1 columns over batch ----
__global__ __launch_bounds__(256) void k_part1(const float* __restrict__ x,
        const float* __restrict__ w1, const float* __restrict__ b1,
        float* __restrict__ p1, int B) {
    float w1r[16], b1r[16], s[16], q[16];
#pragma unroll
    for (int j = 0; j < 16; ++j) { w1r[j] = w1[j]; b1r[j] = b1[j]; s[j] = 0.f; q[j] = 0.f; }
    int tid = threadIdx.x;
    int i = blockIdx.x * 256 + tid;
    if (2 * i < B) {
        f32x2 xv = *(const f32x2*)(x + 2 * i);
#pragma unroll
        for (int e = 0; e < 2; ++e) {
#pragma unroll
            for (int j = 0; j < 16; ++j) {
                float h = leaky(fmaf(xv[e], w1r[j], b1r[j]));
                s[j] += h; q[j] += h * h;
            }
        }
    }
#pragma unroll
    for (int j = 0; j < 16; ++j) {
        for (int off = 32; off >= 1; off >>= 1) {
            s[j] += __shfl_xor(s[j], off, 64);
            q[j] += __shfl_xor(q[j], off, 64);
        }
    }
    __shared__ float red[4][32];
    int w = tid >> 6, lane = tid & 63;
    if (lane == 0) {
#pragma unroll
        for (int j = 0; j < 16; ++j) { red[w][j] = s[j]; red[w][j + 16] = q[j]; }
    }
    __syncthreads();
    if (tid < 32)
        p1[blockIdx.x * 32 + tid] = red[0][tid] + red[1][tid] + red[2][tid] + red[3][tid];
}

// Wave0 helper: fold BN1 + Linear2 into coef[0..15]=a[j], coef[16]=c0.
__device__ __forceinline__ void fold_bn1(const float* __restrict__ p1,
        const float* __restrict__ w2, const float* __restrict__ b2,
        const float* __restrict__ g1, const float* __restrict__ be1,
        float* coef, int tid, float invB) {
    float acc = 0.f;
    for (int i = 0; i < 64; ++i) acc += p1[i * 32 + tid];
    float qacc = __shfl(acc, tid + 16, 64);   // lanes 0..15 fetch sumsq
    float cp = 0.f;
    if (tid < 16) {
        float mean = acc * invB;
        float var  = qacc * invB - mean * mean;
        float inv  = rsqrtf(var + BN_EPS) * g1[tid];
        float sh   = fmaf(-mean, inv, be1[tid]);
        coef[tid] = inv * w2[tid];
        cp = sh * w2[tid];
    }
    for (int off = 8; off >= 1; off >>= 1) cp += __shfl_xor(cp, off, 16);
    if (tid == 0) coef[16] = cp + b2[0];
}

// -------- K2: fold BN1 (block0 publishes coef to ws) + h2 stats partials ---
__global__ __launch_bounds__(256) void k_h2f(const float* __restrict__ x,
        const float* __restrict__ w1, const float* __restrict__ b1,
        const float* __restrict__ p1, const float* __restrict__ w2,
        const float* __restrict__ b2, const float* __restrict__ g1,
        const float* __restrict__ be1, float* __restrict__ p2,
        float* __restrict__ cfws, int B, float invB) {
    __shared__ float coef[17];
    int tid = threadIdx.x;
    if (tid < 32) fold_bn1(p1, w2, b2, g1, be1, coef, tid, invB);
    __syncthreads();
    if (blockIdx.x == 0 && tid < 17) cfws[tid] = coef[tid];
    float w1r[16], b1r[16], ar[16];
#pragma unroll
    for (int j = 0; j < 16; ++j) { w1r[j] = w1[j]; b1r[j] = b1[j]; ar[j] = coef[j]; }
    float c0 = coef[16];
    float s = 0.f, q = 0.f;
    int i = blockIdx.x * 256 + tid;
    if (2 * i < B) {
        f32x2 xv = *(const f32x2*)(x + 2 * i);
#pragma unroll
        for (int e = 0; e < 2; ++e) {
            float acc = c0;
#pragma unroll
            for (int j = 0; j < 16; ++j) {
                float h = leaky(fmaf(xv[e], w1r[j], b1r[j]));
                acc = fmaf(h, ar[j], acc);
            }
            float h2 = leaky(acc);
            s += h2; q += h2 * h2;
        }
    }
    for (int off = 32; off >= 1; off >>= 1) {
        s += __shfl_xor(s, off, 64);
        q += __shfl_xor(q, off, 64);
    }
    __shared__ float red[4][2];
    int w = tid >> 6, lane = tid & 63;
    if (lane == 0) { red[w][0] = s; red[w][1] = q; }
    __syncthreads();
    if (tid == 0) {
        p2[blockIdx.x * 2 + 0] = red[0][0] + red[1][0] + red[2][0] + red[3][0];
        p2[blockIdx.x * 2 + 1] = red[0][1] + red[1][1] + red[2][1] + red[3][1];
    }
}

// ---------------- K3: register tree, 1 row/wave, WHOLE ROW IN REGISTERS ----
// Identical to R6 except the burst stores are CACHED (no nt flag).
__global__ __launch_bounds__(256) void k_tree(const float* __restrict__ x,
        const float* __restrict__ w1, const float* __restrict__ b1,
        const float* __restrict__ g2, const float* __restrict__ be2,
        const float* __restrict__ fcw, const float* __restrict__ fcb,
        const float* __restrict__ p2, const float* __restrict__ cfws,
        float* __restrict__ out, int B, float invB) {
    __shared__ float wl[1024], bl[1024];
    __shared__ float x2s[4];       // h2 per block-row
    __shared__ float bn2[2];       // s2, t2
    int tid = threadIdx.x;

    // Stage fc weights raw, swizzled slot-major (same map as R3).
    for (int i = tid; i < 1024; i += 256) {
        int d;
        if (i < 128)      d = i;
        else if (i < 256) { int o = i - 128; d = 128 + ((o & 1) << 6) + (o >> 1); }
        else if (i < 512) { int o = i - 256; d = 256 + ((((o >> 7) << 1) | (o & 1)) << 6) + ((o & 127) >> 1); }
        else              { int o = i - 512; d = 512 + ((((o >> 7) << 1) | (o & 1)) << 6) + ((o & 127) >> 1); }
        wl[d] = fcw[i];
        bl[d] = fcb[i];
    }
    // Wave0: parallel BN2 stats reduce (64 partial pairs)
    if (tid < 64) {
        float s = p2[2 * tid], q = p2[2 * tid + 1];
        for (int off = 32; off >= 1; off >>= 1) {
            s += __shfl_xor(s, off, 64);
            q += __shfl_xor(q, off, 64);
        }
        if (tid == 0) {
            float mean = s * invB, var = q * invB - mean * mean;
            float inv = rsqrtf(var + BN_EPS) * g2[0];
            bn2[0] = inv;
            bn2[1] = fmaf(-mean, inv, be2[0]);
        }
    }
    // Wave1 lanes 0..3: h2 for this block's 4 rows (pre-BN2; BN2 in weights)
    if (tid >= 64 && tid < 68) {
        int rr = tid - 64;
        int r = blockIdx.x * 4 + rr;
        float xv = (r < B) ? x[r] : 0.f;
        float acc = cfws[16];
#pragma unroll
        for (int j = 0; j < 16; ++j) {
            float h = leaky(fmaf(xv, w1[j], b1[j]));
            acc = fmaf(h, cfws[j], acc);
        }
        x2s[rr] = leaky(acc);
    }
    __syncthreads();
    // Fold BN2 into weights: z*log2e = h2*(s2*w*log2e) + (t2*w + b)*log2e
    {
        float s2k = bn2[0] * LOG2E, t2 = bn2[1];
        for (int i = tid; i < 1024; i += 256) {
            float wv = wl[i];
            wl[i] = wv * s2k;
            bl[i] = fmaf(t2, wv, bl[i]) * LOG2E;
        }
    }
    __syncthreads();

    const int w = tid >> 6, lane = tid & 63;
    const int r = blockIdx.x * 4 + w;
    const bool act = r < B;              // wave-uniform
    const float x2 = x2s[w];
    float* op = out + (size_t)r * 2048;

    float s0q[4];                        // segment 0: floats 4*lane .. +3
    float mup;
    // ---- level 1 (uniform across lanes; no shuffle needed) ----
    {
        float z = fmaf(x2, wl[1], bl[1]);
        float pz = sig2(z);
        float c0 = pz, c1 = 1.0f - pz;   // mu parent = 1
        if (lane == 0) { s0q[0] = 0.f; s0q[1] = 1.f; s0q[2] = c0; s0q[3] = c1; }
        mup = (lane & 1) ? c1 : c0;
    }
    // ---- levels 2..6: shuffle levels; gather children into seg0 ----
#pragma unroll
    for (int l = 2; l <= 6; ++l) {
        const int P = 1 << (l - 1);
        float wv = wl[P + lane], bv = bl[P + lane];
        float z = fmaf(x2, wv, bv);
        float pz = sig2(z);
        float c0 = mup * pz, c1 = mup - c0;     // valid in lanes < P
        int sk = (2 * lane - P) & 63;
        float g0 = __shfl(c0, sk, 64);
        float g1 = __shfl(c1, sk, 64);
        float g2 = __shfl(c0, sk + 1, 64);
        float g3 = __shfl(c1, sk + 1, 64);
        if (lane >= P / 2 && lane < P) { s0q[0] = g0; s0q[1] = g1; s0q[2] = g2; s0q[3] = g3; }
        float n0 = __shfl(c0, lane >> 1, 64);
        float n1 = __shfl(c1, lane >> 1, 64);
        mup = (lane & 1) ? n1 : n0;
    }
    // ---- level 7: parent 64+lane; children stay in-lane + gather seg0 ----
    float c2v[2];
    {
        float wv = wl[64 + lane], bv = bl[64 + lane];
        float z = fmaf(x2, wv, bv);
        float pz = sig2(z);
        c2v[0] = mup * pz;
        c2v[1] = mup - c2v[0];
        int sk = (2 * lane - 64) & 63;
        float g0 = __shfl(c2v[0], sk, 64);
        float g1 = __shfl(c2v[1], sk, 64);
        float g2 = __shfl(c2v[0], sk + 1, 64);
        float g3 = __shfl(c2v[1], sk + 1, 64);
        if (lane >= 32) { s0q[0] = g0; s0q[1] = g1; s0q[2] = g2; s0q[3] = g3; }
    }
    // ---- level 8: parents {128+2i, 128+2i+1}; mus in-lane (c2v) ----
    float c4v[4];
#pragma unroll
    for (int s = 0; s < 2; ++s) {
        float wv = wl[128 + (s << 6) + lane], bv = bl[128 + (s << 6) + lane];
        float z = fmaf(x2, wv, bv);
        float pz = sig2(z);
        c4v[2 * s]     = c2v[s] * pz;
        c4v[2 * s + 1] = c2v[s] - c4v[2 * s];
    }
    // ---- level 9: parents {256 + j2*128 + 2i + s}; mus from lane j2*32+(i>>1)
    float c8v[2][4];
#pragma unroll
    for (int j2 = 0; j2 < 2; ++j2) {
        int src = (j2 << 5) + (lane >> 1);
        float A  = __shfl(c4v[0], src, 64);
        float Bv = __shfl(c4v[1], src, 64);
        float C  = __shfl(c4v[2], src, 64);
        float D  = __shfl(c4v[3], src, 64);
        float m0 = (lane & 1) ? C : A;
        float m1 = (lane & 1) ? D : Bv;
        float wv0 = wl[256 + ((2 * j2) << 6) + lane],     bv0 = bl[256 + ((2 * j2) << 6) + lane];
        float wv1 = wl[256 + ((2 * j2 + 1) << 6) + lane], bv1 = bl[256 + ((2 * j2 + 1) << 6) + lane];
        float z0 = fmaf(x2, wv0, bv0);
        float z1 = fmaf(x2, wv1, bv1);
        float p0 = sig2(z0), p1v = sig2(z1);
        c8v[j2][0] = m0 * p0;
        c8v[j2][1] = m0 - c8v[j2][0];
        c8v[j2][2] = m1 * p1v;
        c8v[j2][3] = m1 - c8v[j2][2];
    }
    // ---- level 10: parents {512 + j*128 + 2i + s}; keep results in regs ----
    float l10[4][4];
#pragma unroll
    for (int j = 0; j < 4; ++j) {
        const int j2 = j >> 1;
        int src = ((j & 1) << 5) + (lane >> 1);
        float A  = __shfl(c8v[j2][0], src, 64);
        float Bv = __shfl(c8v[j2][1], src, 64);
        float C  = __shfl(c8v[j2][2], src, 64);
        float D  = __shfl(c8v[j2][3], src, 64);
        float m0 = (lane & 1) ? C : A;
        float m1 = (lane & 1) ? D : Bv;
        float wv0 = wl[512 + ((2 * j) << 6) + lane],     bv0 = bl[512 + ((2 * j) << 6) + lane];
        float wv1 = wl[512 + ((2 * j + 1) << 6) + lane], bv1 = bl[512 + ((2 * j + 1) << 6) + lane];
        float z0 = fmaf(x2, wv0, bv0);
        float z1 = fmaf(x2, wv1, bv1);
        float p0 = sig2(z0), p1v = sig2(z1);
        l10[j][0] = m0 * p0;
        l10[j][1] = m0 - l10[j][0];
        l10[j][2] = m1 * p1v;
        l10[j][3] = m1 - l10[j][2];
    }
    // ---- burst: 8 back-to-back lane-contiguous dwordx4 CACHED stores ----
    if (act) {
        const int o4 = lane << 2;
        st4(op + o4,        s0q[0],    s0q[1],    s0q[2],    s0q[3]);
        st4(op + 256 + o4,  c4v[0],    c4v[1],    c4v[2],    c4v[3]);
        st4(op + 512 + o4,  c8v[0][0], c8v[0][1], c8v[0][2], c8v[0][3]);
        st4(op + 768 + o4,  c8v[1][0], c8v[1][1], c8v[1][2], c8v[1][3]);
        st4(op + 1024 + o4, l10[0][0], l10[0][1], l10[0][2], l10[0][3]);
        st4(op + 1280 + o4, l10[1][0], l10[1][1], l10[1][2], l10[1][3]);
        st4(op + 1536 + o4, l10[2][0], l10[2][1], l10[2][2], l10[2][3]);
        st4(op + 1792 + o4, l10[3][0], l10[3][1], l10[3][2], l10[3][3]);
    }
}

extern "C" void kernel_launch(void* const* d_in, const int* in_sizes, int n_in,
                              void* d_out, int out_size, void* d_ws, size_t ws_size,
                              hipStream_t stream) {
    const float* x   = (const float*)d_in[0];
    const float* w1  = (const float*)d_in[1];
    const float* b1  = (const float*)d_in[2];
    const float* g1  = (const float*)d_in[3];
    const float* be1 = (const float*)d_in[4];
    const float* w2  = (const float*)d_in[5];
    const float* b2  = (const float*)d_in[6];
    const float* g2  = (const float*)d_in[7];
    const float* be2 = (const float*)d_in[8];
    const float* fcw = (const float*)d_in[9];
    const float* fcb = (const float*)d_in[10];
    float* out = (float*)d_out;
    int B = in_sizes[0];
    float invB = 1.0f / (float)B;

    float* ws = (float*)d_ws;
    float* p1 = ws;          // 64*32 partials for BN1
    float* p2 = ws + 2048;   // 64*2 partials for BN2
    float* cf = ws + 2176;   // folded BN1+Linear2 coef [17]

    k_part1<<<64, 256, 0, stream>>>(x, w1, b1, p1, B);
    k_h2f  <<<64, 256, 0, stream>>>(x, w1, b1, p1, w2, b2, g1, be1, p2, cf, B, invB);

    int blocks = (B + 3) / 4;   // 4 rows per block, 1 row per wave
    k_tree<<<blocks, 256, 0, stream>>>(x, w1, b1, g2, be2, fcw, fcb, p2, cf,
                                       out, B, invB);
}

// Round 8
// 57.793 us; speedup vs baseline: 1.1502x; 1.0416x over previous
//
#include <hip/hip_runtime.h>

#define LEAKY_S 0.01f
#define BN_EPS 1e-5f
#define LOG2E 1.44269504088896340736f

typedef float f32x2 __attribute__((ext_vector_type(2)));
typedef float f32x4 __attribute__((ext_vector_type(4)));

__device__ __forceinline__ float leaky(float v) { return v >= 0.0f ? v : LEAKY_S * v; }
__device__ __forceinline__ float fast_exp2(float v) { return __builtin_amdgcn_exp2f(v); }
// sigmoid(z) with weights pre-scaled by log2e
__device__ __forceinline__ float sig2(float z2) {
    return __builtin_amdgcn_rcpf(1.0f + fast_exp2(-z2));
}
__device__ __forceinline__ void st4(float* p, float a, float b, float c, float d) {
    f32x4 v = {a, b, c, d}; *(f32x4*)p = v;   // cached store (R7 winner)
}

// ---------------- K1: partial sums (sum, sumsq) of h1 columns over batch ----
__global__ __launch_bounds__(256) void k_part1(const float* __restrict__ x,
        const float* __restrict__ w1, const float* __restrict__ b1,
        float* __restrict__ p1, int B) {
    float w1r[16], b1r[16], s[16], q[16];
#pragma unroll
    for (int j = 0; j < 16; ++j) { w1r[j] = w1[j]; b1r[j] = b1[j]; s[j] = 0.f; q[j] = 0.f; }
    int tid = threadIdx.x;
    int i = blockIdx.x * 256 + tid;
    if (2 * i < B) {
        f32x2 xv = *(const f32x2*)(x + 2 * i);
#pragma unroll
        for (int e = 0; e < 2; ++e) {
#pragma unroll
            for (int j = 0; j < 16; ++j) {
                float h = leaky(fmaf(xv[e], w1r[j], b1r[j]));
                s[j] += h; q[j] += h * h;
            }
        }
    }
#pragma unroll
    for (int j = 0; j < 16; ++j) {
        for (int off = 32; off >= 1; off >>= 1) {
            s[j] += __shfl_xor(s[j], off, 64);
            q[j] += __shfl_xor(q[j], off, 64);
        }
    }
    __shared__ float red[4][32];
    int w = tid >> 6, lane = tid & 63;
    if (lane == 0) {
#pragma unroll
        for (int j = 0; j < 16; ++j) { red[w][j] = s[j]; red[w][j + 16] = q[j]; }
    }
    __syncthreads();
    if (tid < 32)
        p1[blockIdx.x * 32 + tid] = red[0][tid] + red[1][tid] + red[2][tid] + red[3][tid];
}

// Wave0 helper: fold BN1 + Linear2 into coef[0..15]=a[j], coef[16]=c0.
__device__ __forceinline__ void fold_bn1(const float* __restrict__ p1,
        const float* __restrict__ w2, const float* __restrict__ b2,
        const float* __restrict__ g1, const float* __restrict__ be1,
        float* coef, int tid, float invB) {
    float acc = 0.f;
    for (int i = 0; i < 64; ++i) acc += p1[i * 32 + tid];
    float qacc = __shfl(acc, tid + 16, 64);   // lanes 0..15 fetch sumsq
    float cp = 0.f;
    if (tid < 16) {
        float mean = acc * invB;
        float var  = qacc * invB - mean * mean;
        float inv  = rsqrtf(var + BN_EPS) * g1[tid];
        float sh   = fmaf(-mean, inv, be1[tid]);
        coef[tid] = inv * w2[tid];
        cp = sh * w2[tid];
    }
    for (int off = 8; off >= 1; off >>= 1) cp += __shfl_xor(cp, off, 16);
    if (tid == 0) coef[16] = cp + b2[0];
}

// -------- K2: fold BN1 (block0 publishes coef to ws) + h2 stats partials ---
__global__ __launch_bounds__(256) void k_h2f(const float* __restrict__ x,
        const float* __restrict__ w1, const float* __restrict__ b1,
        const float* __restrict__ p1, const float* __restrict__ w2,
        const float* __restrict__ b2, const float* __restrict__ g1,
        const float* __restrict__ be1, float* __restrict__ p2,
        float* __restrict__ cfws, int B, float invB) {
    __shared__ float coef[17];
    int tid = threadIdx.x;
    if (tid < 32) fold_bn1(p1, w2, b2, g1, be1, coef, tid, invB);
    __syncthreads();
    if (blockIdx.x == 0 && tid < 17) cfws[tid] = coef[tid];
    float w1r[16], b1r[16], ar[16];
#pragma unroll
    for (int j = 0; j < 16; ++j) { w1r[j] = w1[j]; b1r[j] = b1[j]; ar[j] = coef[j]; }
    float c0 = coef[16];
    float s = 0.f, q = 0.f;
    int i = blockIdx.x * 256 + tid;
    if (2 * i < B) {
        f32x2 xv = *(const f32x2*)(x + 2 * i);
#pragma unroll
        for (int e = 0; e < 2; ++e) {
            float acc = c0;
#pragma unroll
            for (int j = 0; j < 16; ++j) {
                float h = leaky(fmaf(xv[e], w1r[j], b1r[j]));
                acc = fmaf(h, ar[j], acc);
            }
            float h2 = leaky(acc);
            s += h2; q += h2 * h2;
        }
    }
    for (int off = 32; off >= 1; off >>= 1) {
        s += __shfl_xor(s, off, 64);
        q += __shfl_xor(q, off, 64);
    }
    __shared__ float red[4][2];
    int w = tid >> 6, lane = tid & 63;
    if (lane == 0) { red[w][0] = s; red[w][1] = q; }
    __syncthreads();
    if (tid == 0) {
        p2[blockIdx.x * 2 + 0] = red[0][0] + red[1][0] + red[2][0] + red[3][0];
        p2[blockIdx.x * 2 + 1] = red[0][1] + red[1][1] + red[2][1] + red[3][1];
    }
}

// ---------------- K3: register tree, 4 rows per wave (loop), 16 rows/block -
// Prologue (weight stage + BN2 fold) amortized over 4 row-iterations; the
// per-row body is R7's register tree with the cached dwordx4 burst.
__global__ __launch_bounds__(256, 4) void k_tree(const float* __restrict__ x,
        const float* __restrict__ w1, const float* __restrict__ b1,
        const float* __restrict__ g2, const float* __restrict__ be2,
        const float* __restrict__ fcw, const float* __restrict__ fcb,
        const float* __restrict__ p2, const float* __restrict__ cfws,
        float* __restrict__ out, int B, float invB) {
    __shared__ float wl[1024], bl[1024];
    __shared__ float x2s[16];      // h2 per block-row
    __shared__ float bn2[2];       // s2, t2
    int tid = threadIdx.x;

    // Stage fc weights raw, swizzled slot-major (same map as R3).
    for (int i = tid; i < 1024; i += 256) {
        int d;
        if (i < 128)      d = i;
        else if (i < 256) { int o = i - 128; d = 128 + ((o & 1) << 6) + (o >> 1); }
        else if (i < 512) { int o = i - 256; d = 256 + ((((o >> 7) << 1) | (o & 1)) << 6) + ((o & 127) >> 1); }
        else              { int o = i - 512; d = 512 + ((((o >> 7) << 1) | (o & 1)) << 6) + ((o & 127) >> 1); }
        wl[d] = fcw[i];
        bl[d] = fcb[i];
    }
    // Wave0: parallel BN2 stats reduce (64 partial pairs)
    if (tid < 64) {
        float s = p2[2 * tid], q = p2[2 * tid + 1];
        for (int off = 32; off >= 1; off >>= 1) {
            s += __shfl_xor(s, off, 64);
            q += __shfl_xor(q, off, 64);
        }
        if (tid == 0) {
            float mean = s * invB, var = q * invB - mean * mean;
            float inv = rsqrtf(var + BN_EPS) * g2[0];
            bn2[0] = inv;
            bn2[1] = fmaf(-mean, inv, be2[0]);
        }
    }
    // Wave1 lanes 0..15: h2 for this block's 16 rows (pre-BN2; BN2 in weights)
    if (tid >= 64 && tid < 80) {
        int rr = tid - 64;
        int r = blockIdx.x * 16 + rr;
        float xv = (r < B) ? x[r] : 0.f;
        float acc = cfws[16];
#pragma unroll
        for (int j = 0; j < 16; ++j) {
            float h = leaky(fmaf(xv, w1[j], b1[j]));
            acc = fmaf(h, cfws[j], acc);
        }
        x2s[rr] = leaky(acc);
    }
    __syncthreads();
    // Fold BN2 into weights: z*log2e = h2*(s2*w*log2e) + (t2*w + b)*log2e
    {
        float s2k = bn2[0] * LOG2E, t2 = bn2[1];
        for (int i = tid; i < 1024; i += 256) {
            float wv = wl[i];
            wl[i] = wv * s2k;
            bl[i] = fmaf(t2, wv, bl[i]) * LOG2E;
        }
    }
    __syncthreads();

    const int w = tid >> 6, lane = tid & 63;
#pragma unroll 1
    for (int it = 0; it < 4; ++it) {
        const int r = blockIdx.x * 16 + w * 4 + it;
        const bool act = r < B;              // wave-uniform
        const float x2 = x2s[w * 4 + it];
        float* op = out + (size_t)r * 2048;

        float s0q[4];                        // segment 0: floats 4*lane .. +3
        float mup;
        // ---- level 1 (uniform across lanes; no shuffle needed) ----
        {
            float z = fmaf(x2, wl[1], bl[1]);
            float pz = sig2(z);
            float c0 = pz, c1 = 1.0f - pz;   // mu parent = 1
            if (lane == 0) { s0q[0] = 0.f; s0q[1] = 1.f; s0q[2] = c0; s0q[3] = c1; }
            mup = (lane & 1) ? c1 : c0;
        }
        // ---- levels 2..6: shuffle levels; gather children into seg0 ----
#pragma unroll
        for (int l = 2; l <= 6; ++l) {
            const int P = 1 << (l - 1);
            float wv = wl[P + lane], bv = bl[P + lane];
            float z = fmaf(x2, wv, bv);
            float pz = sig2(z);
            float c0 = mup * pz, c1 = mup - c0;     // valid in lanes < P
            int sk = (2 * lane - P) & 63;
            float g0 = __shfl(c0, sk, 64);
            float g1 = __shfl(c1, sk, 64);
            float g2 = __shfl(c0, sk + 1, 64);
            float g3 = __shfl(c1, sk + 1, 64);
            if (lane >= P / 2 && lane < P) { s0q[0] = g0; s0q[1] = g1; s0q[2] = g2; s0q[3] = g3; }
            float n0 = __shfl(c0, lane >> 1, 64);
            float n1 = __shfl(c1, lane >> 1, 64);
            mup = (lane & 1) ? n1 : n0;
        }
        // ---- level 7: parent 64+lane; children stay in-lane + gather seg0 ----
        float c2v[2];
        {
            float wv = wl[64 + lane], bv = bl[64 + lane];
            float z = fmaf(x2, wv, bv);
            float pz = sig2(z);
            c2v[0] = mup * pz;
            c2v[1] = mup - c2v[0];
            int sk = (2 * lane - 64) & 63;
            float g0 = __shfl(c2v[0], sk, 64);
            float g1 = __shfl(c2v[1], sk, 64);
            float g2 = __shfl(c2v[0], sk + 1, 64);
            float g3 = __shfl(c2v[1], sk + 1, 64);
            if (lane >= 32) { s0q[0] = g0; s0q[1] = g1; s0q[2] = g2; s0q[3] = g3; }
        }
        // ---- level 8: parents {128+2i, 128+2i+1}; mus in-lane (c2v) ----
        float c4v[4];
#pragma unroll
        for (int s = 0; s < 2; ++s) {
            float wv = wl[128 + (s << 6) + lane], bv = bl[128 + (s << 6) + lane];
            float z = fmaf(x2, wv, bv);
            float pz = sig2(z);
            c4v[2 * s]     = c2v[s] * pz;
            c4v[2 * s + 1] = c2v[s] - c4v[2 * s];
        }
        // ---- level 9: parents {256 + j2*128 + 2i + s} ----
        float c8v[2][4];
#pragma unroll
        for (int j2 = 0; j2 < 2; ++j2) {
            int src = (j2 << 5) + (lane >> 1);
            float A  = __shfl(c4v[0], src, 64);
            float Bv = __shfl(c4v[1], src, 64);
            float C  = __shfl(c4v[2], src, 64);
            float D  = __shfl(c4v[3], src, 64);
            float m0 = (lane & 1) ? C : A;
            float m1 = (lane & 1) ? D : Bv;
            float wv0 = wl[256 + ((2 * j2) << 6) + lane],     bv0 = bl[256 + ((2 * j2) << 6) + lane];
            float wv1 = wl[256 + ((2 * j2 + 1) << 6) + lane], bv1 = bl[256 + ((2 * j2 + 1) << 6) + lane];
            float z0 = fmaf(x2, wv0, bv0);
            float z1 = fmaf(x2, wv1, bv1);
            float p0 = sig2(z0), p1v = sig2(z1);
            c8v[j2][0] = m0 * p0;
            c8v[j2][1] = m0 - c8v[j2][0];
            c8v[j2][2] = m1 * p1v;
            c8v[j2][3] = m1 - c8v[j2][2];
        }
        // ---- level 10: parents {512 + j*128 + 2i + s} ----
        float l10[4][4];
#pragma unroll
        for (int j = 0; j < 4; ++j) {
            const int j2 = j >> 1;
            int src = ((j & 1) << 5) + (lane >> 1);
            float A  = __shfl(c8v[j2][0], src, 64);
            float Bv = __shfl(c8v[j2][1], src, 64);
            float C  = __shfl(c8v[j2][2], src, 64);
            float D  = __shfl(c8v[j2][3], src, 64);
            float m0 = (lane & 1) ? C : A;
            float m1 = (lane & 1) ? D : Bv;
            float wv0 = wl[512 + ((2 * j) << 6) + lane],     bv0 = bl[512 + ((2 * j) << 6) + lane];
            float wv1 = wl[512 + ((2 * j + 1) << 6) + lane], bv1 = bl[512 + ((2 * j + 1) << 6) + lane];
            float z0 = fmaf(x2, wv0, bv0);
            float z1 = fmaf(x2, wv1, bv1);
            float p0 = sig2(z0), p1v = sig2(z1);
            l10[j][0] = m0 * p0;
            l10[j][1] = m0 - l10[j][0];
            l10[j][2] = m1 * p1v;
            l10[j][3] = m1 - l10[j][2];
        }
        // ---- burst: 8 back-to-back lane-contiguous dwordx4 cached stores ----
        if (act) {
            const int o4 = lane << 2;
            st4(op + o4,        s0q[0],    s0q[1],    s0q[2],    s0q[3]);
            st4(op + 256 + o4,  c4v[0],    c4v[1],    c4v[2],    c4v[3]);
            st4(op + 512 + o4,  c8v[0][0], c8v[0][1], c8v[0][2], c8v[0][3]);
            st4(op + 768 + o4,  c8v[1][0], c8v[1][1], c8v[1][2], c8v[1][3]);
            st4(op + 1024 + o4, l10[0][0], l10[0][1], l10[0][2], l10[0][3]);
            st4(op + 1280 + o4, l10[1][0], l10[1][1], l10[1][2], l10[1][3]);
            st4(op + 1536 + o4, l10[2][0], l10[2][1], l10[2][2], l10[2][3]);
            st4(op + 1792 + o4, l10[3][0], l10[3][1], l10[3][2], l10[3][3]);
        }
    }
}

extern "C" void kernel_launch(void* const* d_in, const int* in_sizes, int n_in,
                              void* d_out, int out_size, void* d_ws, size_t ws_size,
                              hipStream_t stream) {
    const float* x   = (const float*)d_in[0];
    const float* w1  = (const float*)d_in[1];
    const float* b1  = (const float*)d_in[2];
    const float* g1  = (const float*)d_in[3];
    const float* be1 = (const float*)d_in[4];
    const float* w2  = (const float*)d_in[5];
    const float* b2  = (const float*)d_in[6];
    const float* g2  = (const float*)d_in[7];
    const float* be2 = (const float*)d_in[8];
    const float* fcw = (const float*)d_in[9];
    const float* fcb = (const float*)d_in[10];
    float* out = (float*)d_out;
    int B = in_sizes[0];
    float invB = 1.0f / (float)B;

    float* ws = (float*)d_ws;
    float* p1 = ws;          // 64*32 partials for BN1
    float* p2 = ws + 2048;   // 64*2 partials for BN2
    float* cf = ws + 2176;   // folded BN1+Linear2 coef [17]

    k_part1<<<64, 256, 0, stream>>>(x, w1, b1, p1, B);
    k_h2f  <<<64, 256, 0, stream>>>(x, w1, b1, p1, w2, b2, g1, be1, p2, cf, B, invB);

    int blocks = (B + 15) / 16;   // 16 rows per block, 4 rows per wave (loop)
    k_tree<<<blocks, 256, 0, stream>>>(x, w1, b1, g2, be2, fcw, fcb, p2, cf,
                                       out, B, invB);
}